// Round 2
// baseline (441.725 us; speedup 1.0000x reference)
//
#include <hip/hip_runtime.h>
#include <cstdint>
#include <cstddef>

// CausalAttention B=4 S=2048 D=1024.
// d_out = [context (4*2048*1024 f32)] ++ [attn_scores (4*2048*2048 f32)]
//
// Precision design: scores ~ 256*S_q*S_k (up to ~1e6 unscaled) feed a softmax;
// plain-bf16 QK^T gives ~0.7 scaled-unit score error -> argmax flips on soft
// rows -> O(100) context error (round-1 failure). Fix: split-bf16 (hi+lo)
// 3-pass MFMA for x@Wq, x@Wk and Q@K^T (~2^-17 relative). V path and P@V
// remain plain bf16 (elementwise-bounded, ~0.3 absmax).

#define S_LEN 2048
#define D_DIM 1024
#define NBATCH 4
#define MEG (1024 * 1024)

typedef __attribute__((ext_vector_type(4))) float floatx4;
typedef __attribute__((ext_vector_type(8))) __bf16 bf16x8;
typedef __attribute__((ext_vector_type(8))) short short8v;

__device__ __forceinline__ unsigned short f2bf(float f) {
  union { float f; unsigned u; } v; v.f = f;
  unsigned r = v.u + 0x7FFF + ((v.u >> 16) & 1);   // round-to-nearest-even
  return (unsigned short)(r >> 16);
}
__device__ __forceinline__ float bf2f(unsigned short h) {
  union { unsigned u; float f; } v; v.u = ((unsigned)h) << 16; return v.f;
}

__device__ __forceinline__ void async_copy16(const void* g, void* l) {
  __builtin_amdgcn_global_load_lds(
      (const __attribute__((address_space(1))) void*)g,
      (__attribute__((address_space(3))) void*)l, 16, 0, 0);
}

// ---------------- plain bf16 core: C[M,N] += A[M,K] * B[N,K]^T ----------------
// 128x128 block, BK=32, 256 threads, m97 structure.
__device__ __forceinline__ void gemm_bt_core(
    const short* __restrict__ A, const short* __restrict__ B,
    int lda, int ldb, int kIters, int blockM, int blockN,
    short (*As)[32], short (*Bs)[32], floatx4 (&acc)[4][4])
{
  const int tid  = threadIdx.x;
  const int lane = tid & 63;
  const int wave = tid >> 6;
  const int wm = (wave >> 1) * 64;
  const int wn = (wave & 1) * 64;
  const int fm = lane & 15;
  const int fk = (lane >> 4) * 8;
  const int r0 = tid >> 2;
  const int c0 = (tid & 3) * 8;

  floatx4 zero = {0.f, 0.f, 0.f, 0.f};
  #pragma unroll
  for (int i = 0; i < 4; ++i)
    #pragma unroll
    for (int j = 0; j < 4; ++j)
      acc[i][j] = zero;

  const short* a0 = A + (size_t)(blockM + r0) * lda + c0;
  const short* a1 = a0 + (size_t)64 * lda;
  const short* b0 = B + (size_t)(blockN + r0) * ldb + c0;
  const short* b1 = b0 + (size_t)64 * ldb;
  short* as0 = &As[r0][c0];
  short* as1 = &As[r0 + 64][c0];
  short* bs0 = &Bs[r0][c0];
  short* bs1 = &Bs[r0 + 64][c0];

  for (int kt = 0; kt < kIters; ++kt) {
    const int kb = kt * 32;
    async_copy16(a0 + kb, as0);
    async_copy16(a1 + kb, as1);
    async_copy16(b0 + kb, bs0);
    async_copy16(b1 + kb, bs1);
    __syncthreads();
    bf16x8 af[4], bfr[4];
    #pragma unroll
    for (int i = 0; i < 4; ++i)
      af[i] = *(const bf16x8*)(&As[wm + i * 16 + fm][fk]);
    #pragma unroll
    for (int j = 0; j < 4; ++j)
      bfr[j] = *(const bf16x8*)(&Bs[wn + j * 16 + fm][fk]);
    #pragma unroll
    for (int i = 0; i < 4; ++i)
      #pragma unroll
      for (int j = 0; j < 4; ++j)
        acc[i][j] = __builtin_amdgcn_mfma_f32_16x16x32_bf16(af[i], bfr[j], acc[i][j], 0, 0, 0);
    __syncthreads();
  }
}

// ---------------- split core: A,B given as hi/lo bf16 planes ----------------
// acc += (Ah+Al) * (Bh+Bl)^T via hh + hl + lh (lo*lo dropped, ~2^-16 rel).
__device__ __forceinline__ void gemm_bt_split_core(
    const short* __restrict__ Ah, const short* __restrict__ Al,
    const short* __restrict__ Bh, const short* __restrict__ Bl,
    int lda, int ldb, int kIters, int blockM, int blockN,
    short (*AsH)[32], short (*AsL)[32], short (*BsH)[32], short (*BsL)[32],
    floatx4 (&acc)[4][4])
{
  const int tid  = threadIdx.x;
  const int lane = tid & 63;
  const int wave = tid >> 6;
  const int wm = (wave >> 1) * 64;
  const int wn = (wave & 1) * 64;
  const int fm = lane & 15;
  const int fk = (lane >> 4) * 8;
  const int r0 = tid >> 2;
  const int c0 = (tid & 3) * 8;

  floatx4 zero = {0.f, 0.f, 0.f, 0.f};
  #pragma unroll
  for (int i = 0; i < 4; ++i)
    #pragma unroll
    for (int j = 0; j < 4; ++j)
      acc[i][j] = zero;

  const size_t oa0 = (size_t)(blockM + r0) * lda + c0;
  const size_t oa1 = oa0 + (size_t)64 * lda;
  const size_t ob0 = (size_t)(blockN + r0) * ldb + c0;
  const size_t ob1 = ob0 + (size_t)64 * ldb;
  short* lah0 = &AsH[r0][c0]; short* lah1 = &AsH[r0 + 64][c0];
  short* lal0 = &AsL[r0][c0]; short* lal1 = &AsL[r0 + 64][c0];
  short* lbh0 = &BsH[r0][c0]; short* lbh1 = &BsH[r0 + 64][c0];
  short* lbl0 = &BsL[r0][c0]; short* lbl1 = &BsL[r0 + 64][c0];

  for (int kt = 0; kt < kIters; ++kt) {
    const int kb = kt * 32;
    async_copy16(Ah + oa0 + kb, lah0);
    async_copy16(Ah + oa1 + kb, lah1);
    async_copy16(Al + oa0 + kb, lal0);
    async_copy16(Al + oa1 + kb, lal1);
    async_copy16(Bh + ob0 + kb, lbh0);
    async_copy16(Bh + ob1 + kb, lbh1);
    async_copy16(Bl + ob0 + kb, lbl0);
    async_copy16(Bl + ob1 + kb, lbl1);
    __syncthreads();
    bf16x8 ah[4], al[4], bh[4], bl[4];
    #pragma unroll
    for (int i = 0; i < 4; ++i) {
      ah[i] = *(const bf16x8*)(&AsH[wm + i * 16 + fm][fk]);
      al[i] = *(const bf16x8*)(&AsL[wm + i * 16 + fm][fk]);
    }
    #pragma unroll
    for (int j = 0; j < 4; ++j) {
      bh[j] = *(const bf16x8*)(&BsH[wn + j * 16 + fm][fk]);
      bl[j] = *(const bf16x8*)(&BsL[wn + j * 16 + fm][fk]);
    }
    #pragma unroll
    for (int i = 0; i < 4; ++i)
      #pragma unroll
      for (int j = 0; j < 4; ++j) {
        acc[i][j] = __builtin_amdgcn_mfma_f32_16x16x32_bf16(ah[i], bh[j], acc[i][j], 0, 0, 0);
        acc[i][j] = __builtin_amdgcn_mfma_f32_16x16x32_bf16(ah[i], bl[j], acc[i][j], 0, 0, 0);
        acc[i][j] = __builtin_amdgcn_mfma_f32_16x16x32_bf16(al[i], bh[j], acc[i][j], 0, 0, 0);
      }
    __syncthreads();
  }
}

// ---------------- conversion kernels ----------------

__global__ __launch_bounds__(256) void k_cvt_x_split(const float4* __restrict__ x,
                                                     short* __restrict__ xh,
                                                     short* __restrict__ xl) {
  const size_t idx = (size_t)blockIdx.x * 256 + threadIdx.x;
  const float4 u = x[idx * 2];
  const float4 w = x[idx * 2 + 1];
  float f[8] = {u.x, u.y, u.z, u.w, w.x, w.y, w.z, w.w};
  short8v oh, ol;
  #pragma unroll
  for (int e = 0; e < 8; ++e) {
    const unsigned short h = f2bf(f[e]);
    oh[e] = (short)h;
    ol[e] = (short)f2bf(f[e] - bf2f(h));
  }
  *(short8v*)(xh + idx * 8) = oh;
  *(short8v*)(xl + idx * 8) = ol;
}

// W[k][n] f32 -> wth[n][k] (+ wtl for Q,K) bf16, transposed via 32x32 LDS tile.
__global__ __launch_bounds__(256) void k_cvt_w(
    const float* __restrict__ wq, const float* __restrict__ wk,
    const float* __restrict__ wv, short* __restrict__ wth,
    short* __restrict__ wtl)
{
  const int z = blockIdx.z;
  const float* W = (z == 0) ? wq : (z == 1) ? wk : wv;
  short* outh = wth + (size_t)z * D_DIM * D_DIM;
  short* outl = wtl + (size_t)z * D_DIM * D_DIM;   // only valid for z<2
  __shared__ float tile[32][33];
  const int tx = threadIdx.x, ty = threadIdx.y;
  const int colIn = blockIdx.x * 32 + tx;
  #pragma unroll
  for (int i = 0; i < 4; ++i) {
    const int rowIn = blockIdx.y * 32 + ty + i * 8;
    tile[ty + i * 8][tx] = W[(size_t)rowIn * D_DIM + colIn];
  }
  __syncthreads();
  const int colOut = blockIdx.y * 32 + tx;   // k
  #pragma unroll
  for (int i = 0; i < 4; ++i) {
    const int rowOut = blockIdx.x * 32 + ty + i * 8;  // n
    const float val = tile[tx][ty + i * 8];
    const unsigned short h = f2bf(val);
    outh[(size_t)rowOut * D_DIM + colOut] = (short)h;
    if (z < 2)
      outl[(size_t)rowOut * D_DIM + colOut] = (short)f2bf(val - bf2f(h));
  }
}

// ---------------- GEMM kernels ----------------

// Q,K = x @ [Wq|Wk], split precision; outputs stored as hi/lo bf16 planes.
__global__ __launch_bounds__(256) void k_gemm_qk(
    const short* __restrict__ xh, const short* __restrict__ xl,
    const short* __restrict__ wth, const short* __restrict__ wtl,
    short* __restrict__ qh, short* __restrict__ ql,
    short* __restrict__ kh, short* __restrict__ kl)
{
  __shared__ alignas(16) short AsH[128][32];
  __shared__ alignas(16) short AsL[128][32];
  __shared__ alignas(16) short BsH[128][32];
  __shared__ alignas(16) short BsL[128][32];
  floatx4 acc[4][4];
  const int blockM = blockIdx.y * 128;
  const int blockN = blockIdx.x * 128;   // 0..2047 over [Q|K]
  gemm_bt_split_core(xh, xl, wth, wtl, D_DIM, D_DIM, D_DIM / 32,
                     blockM, blockN, AsH, AsL, BsH, BsL, acc);

  const int tid = threadIdx.x, lane = tid & 63, wave = tid >> 6;
  const int wm = (wave >> 1) * 64, wn = (wave & 1) * 64;
  const int rb = wm + ((lane >> 4) << 2);
  const int cb = wn + (lane & 15);
  const bool isQ = (blockN < D_DIM);
  short* dh = isQ ? qh : kh;
  short* dl = isQ ? ql : kl;
  const int coff = isQ ? blockN : blockN - D_DIM;
  #pragma unroll
  for (int i = 0; i < 4; ++i)
    #pragma unroll
    for (int j = 0; j < 4; ++j) {
      const int n = coff + cb + j * 16;
      #pragma unroll
      for (int r = 0; r < 4; ++r) {
        const int m = blockM + rb + i * 16 + r;
        const float f = acc[i][j][r];
        const unsigned short h = f2bf(f);
        dh[(size_t)m * D_DIM + n] = (short)h;
        dl[(size_t)m * D_DIM + n] = (short)f2bf(f - bf2f(h));
      }
    }
}

// V = x @ Wv, plain bf16, stored transposed vt[b][d][s].
__global__ __launch_bounds__(256) void k_gemm_v(
    const short* __restrict__ xh, const short* __restrict__ wthV,
    short* __restrict__ vt)
{
  __shared__ alignas(16) short As[128][32];
  __shared__ alignas(16) short Bs[128][32];
  floatx4 acc[4][4];
  const int blockM = blockIdx.y * 128;
  const int blockN = blockIdx.x * 128;   // d in 0..1023
  gemm_bt_core(xh, wthV, D_DIM, D_DIM, D_DIM / 32, blockM, blockN, As, Bs, acc);

  const int tid = threadIdx.x, lane = tid & 63, wave = tid >> 6;
  const int wm = (wave >> 1) * 64, wn = (wave & 1) * 64;
  const int rb = wm + ((lane >> 4) << 2);
  const int cb = wn + (lane & 15);
  #pragma unroll
  for (int i = 0; i < 4; ++i)
    #pragma unroll
    for (int j = 0; j < 4; ++j) {
      const int n = blockN + cb + j * 16;   // d index
      const int m0 = blockM + rb + i * 16;  // global row (b,s), 4-aligned
      const int b = m0 >> 11;
      const int s0 = m0 & (S_LEN - 1);
      ushort4 pk;
      pk.x = f2bf(acc[i][j][0]); pk.y = f2bf(acc[i][j][1]);
      pk.z = f2bf(acc[i][j][2]); pk.w = f2bf(acc[i][j][3]);
      *(ushort4*)(vt + ((size_t)b * D_DIM + n) * S_LEN + s0) = pk;
    }
}

// raw scores = Q @ K^T, split precision, lower-triangular blocks only.
__global__ __launch_bounds__(256) void k_gemm_scores(
    const short* __restrict__ qh, const short* __restrict__ ql,
    const short* __restrict__ kh, const short* __restrict__ kl,
    float* __restrict__ attn)
{
  __shared__ alignas(16) short AsH[128][32];
  __shared__ alignas(16) short AsL[128][32];
  __shared__ alignas(16) short BsH[128][32];
  __shared__ alignas(16) short BsL[128][32];
  floatx4 acc[4][4];
  int t = blockIdx.x, bi = 0;
  while (t >= bi + 1) { t -= bi + 1; ++bi; }
  const int bj = t;
  const int b = blockIdx.z;
  const size_t boff = (size_t)b * S_LEN * D_DIM;
  gemm_bt_split_core(qh + boff, ql + boff, kh + boff, kl + boff,
                     D_DIM, D_DIM, D_DIM / 32, bi * 128, bj * 128,
                     AsH, AsL, BsH, BsL, acc);

  float* out = attn + (size_t)b * S_LEN * S_LEN;
  const int tid = threadIdx.x, lane = tid & 63, wave = tid >> 6;
  const int wm = (wave >> 1) * 64, wn = (wave & 1) * 64;
  const int rb = wm + ((lane >> 4) << 2);
  const int cb = wn + (lane & 15);
  #pragma unroll
  for (int i = 0; i < 4; ++i)
    #pragma unroll
    for (int j = 0; j < 4; ++j) {
      const int n = bj * 128 + cb + j * 16;
      #pragma unroll
      for (int r = 0; r < 4; ++r) {
        const int m = bi * 128 + rb + i * 16 + r;
        out[(size_t)m * S_LEN + n] = acc[i][j][r];  // raw, unmasked/unscaled
      }
    }
}

// context = P @ V (plain bf16), K-dim truncated per block-row.
__global__ __launch_bounds__(256) void k_gemm_ctx(
    const short* __restrict__ pb, const short* __restrict__ vt,
    float* __restrict__ ctx)
{
  __shared__ alignas(16) short As[128][32];
  __shared__ alignas(16) short Bs[128][32];
  floatx4 acc[4][4];
  const int b = blockIdx.z;
  const int blockM = blockIdx.y * 128;   // q
  const int blockN = blockIdx.x * 128;   // d
  const int kIters = blockIdx.y * 4 + 4; // k <= blockM+127 only
  const short* A = pb + (size_t)b * S_LEN * S_LEN;
  const short* B = vt + (size_t)b * D_DIM * S_LEN;
  gemm_bt_core(A, B, S_LEN, S_LEN, kIters, blockM, blockN, As, Bs, acc);

  float* out = ctx + (size_t)b * S_LEN * D_DIM;
  const int tid = threadIdx.x, lane = tid & 63, wave = tid >> 6;
  const int wm = (wave >> 1) * 64, wn = (wave & 1) * 64;
  const int rb = wm + ((lane >> 4) << 2);
  const int cb = wn + (lane & 15);
  #pragma unroll
  for (int i = 0; i < 4; ++i)
    #pragma unroll
    for (int j = 0; j < 4; ++j) {
      const int n = blockN + cb + j * 16;
      #pragma unroll
      for (int r = 0; r < 4; ++r) {
        const int m = blockM + rb + i * 16 + r;
        out[(size_t)m * D_DIM + n] = acc[i][j][r];
      }
    }
}

// ---------------- softmax (mask k>q, scale 1/32, write f32 + bf16 P) ----------------

__global__ __launch_bounds__(256) void k_softmax(float* __restrict__ attn,
                                                 short* __restrict__ pb) {
  const int b = blockIdx.x >> 11;
  const int q = blockIdx.x & (S_LEN - 1);
  float* row  = attn + ((size_t)b * S_LEN + q) * S_LEN;
  short* prow = pb   + ((size_t)b * S_LEN + q) * S_LEN;
  const int tid = threadIdx.x;
  __shared__ float sMax[4], sSum[4];
  float v[8];
  float mx = -3.0e38f;
  #pragma unroll
  for (int e = 0; e < 8; ++e) {
    const int k = e * 256 + tid;
    v[e] = (k <= q) ? row[k] : -3.0e38f;   // masked entries never read
    mx = fmaxf(mx, v[e]);
  }
  #pragma unroll
  for (int off = 32; off > 0; off >>= 1) mx = fmaxf(mx, __shfl_xor(mx, off));
  if ((tid & 63) == 0) sMax[tid >> 6] = mx;
  __syncthreads();
  mx = fmaxf(fmaxf(sMax[0], sMax[1]), fmaxf(sMax[2], sMax[3]));

  float s = 0.f;
  #pragma unroll
  for (int e = 0; e < 8; ++e) {
    const int k = e * 256 + tid;
    const float p = (k <= q) ? __expf((v[e] - mx) * 0.03125f) : 0.f;  // 1/sqrt(1024)
    v[e] = p;
    s += p;
  }
  #pragma unroll
  for (int off = 32; off > 0; off >>= 1) s += __shfl_xor(s, off);
  if ((tid & 63) == 0) sSum[tid >> 6] = s;
  __syncthreads();
  s = sSum[0] + sSum[1] + sSum[2] + sSum[3];
  const float inv = 1.0f / s;

  #pragma unroll
  for (int e = 0; e < 8; ++e) {
    const int k = e * 256 + tid;
    const float o = v[e] * inv;            // 0 for masked
    row[k] = o;
    prow[k] = (short)f2bf(o);
  }
}

// ---------------- launch ----------------

extern "C" void kernel_launch(void* const* d_in, const int* in_sizes, int n_in,
                              void* d_out, int out_size, void* d_ws, size_t ws_size,
                              hipStream_t stream) {
  const float* x  = (const float*)d_in[0];
  const float* wq = (const float*)d_in[1];
  const float* wk = (const float*)d_in[2];
  const float* wv = (const float*)d_in[3];

  float* out  = (float*)d_out;
  float* ctx  = out;                                       // [4,2048,1024]
  float* attn = out + (size_t)NBATCH * S_LEN * D_DIM;      // [4,2048,2048]

  // workspace (shorts), ~122 MiB total; pb aliases xh/xl (dead after GEMM1)
  short* ws  = (short*)d_ws;
  short* xh  = ws;                                  // 8M
  short* xl  = xh + (size_t)8 * MEG;                // 8M
  short* pb  = xh;                                  // 16M alias
  short* wth = xl + (size_t)8 * MEG;                // 3M  [Wq^T|Wk^T|Wv^T] hi
  short* wtl = wth + (size_t)3 * MEG;               // 2M  [Wq^T|Wk^T] lo
  short* qh  = wtl + (size_t)2 * MEG;               // 8M
  short* ql  = qh + (size_t)8 * MEG;                // 8M
  short* kh  = ql + (size_t)8 * MEG;                // 8M
  short* kl  = kh + (size_t)8 * MEG;                // 8M
  short* vt  = kl + (size_t)8 * MEG;                // 8M  V^T [b,d,s]

  k_cvt_x_split<<<4096, 256, 0, stream>>>((const float4*)x, xh, xl);
  k_cvt_w<<<dim3(32, 32, 3), dim3(32, 8), 0, stream>>>(wq, wk, wv, wth, wtl);
  k_gemm_qk<<<dim3(16, 64), 256, 0, stream>>>(xh, xl, wth, wtl, qh, ql, kh, kl);
  k_gemm_v<<<dim3(8, 64), 256, 0, stream>>>(xh, wth + (size_t)2 * MEG, vt);
  k_gemm_scores<<<dim3(136, 1, 4), 256, 0, stream>>>(qh, ql, kh, kl, attn);
  k_softmax<<<NBATCH * S_LEN, 256, 0, stream>>>(attn, pb);
  k_gemm_ctx<<<dim3(8, 16, 4), 256, 0, stream>>>(pb, vt, ctx);
}

// Round 4
// 430.856 us; speedup vs baseline: 1.0252x; 1.0252x over previous
//
#include <hip/hip_runtime.h>
#include <cstdint>
#include <cstddef>

// CausalAttention B=4 S=2048 D=1024.
// d_out = [context (4*2048*1024 f32)] ++ [attn_scores (4*2048*2048 f32)]
//
// scores = x M x^T with M[d,e] = sum_i Wq[d,i] Wk[e,i]  (contraction over
// OUTPUT dim i -> M is computed from ORIGINAL-layout Wq,Wk whose inner axis
// is i; round-3 bug was contracting transposed weights over d).
//   M^T = bt(A=Wk, B=Wq)      (split bf16 3-pass, 6.4 GF)
//   N~  = x M - sq*mu^T       (split, 51.5 GF; mean-deflated, |N~|~700)
//   S   = N~ x^T + sq*u       (split, lower-tri; u[k]=mu.x~[k] exact in f32)
// V path and P@V stay plain bf16 (elementwise-bounded, ~0.3 absmax).

#define S_LEN 2048
#define D_DIM 1024
#define NBATCH 4
#define MEG (1024 * 1024)

typedef __attribute__((ext_vector_type(4))) float floatx4;
typedef __attribute__((ext_vector_type(8))) __bf16 bf16x8;
typedef __attribute__((ext_vector_type(8))) short short8v;

__device__ __forceinline__ unsigned short f2bf(float f) {
  union { float f; unsigned u; } v; v.f = f;
  unsigned r = v.u + 0x7FFF + ((v.u >> 16) & 1);   // round-to-nearest-even
  return (unsigned short)(r >> 16);
}
__device__ __forceinline__ float bf2f(unsigned short h) {
  union { unsigned u; float f; } v; v.u = ((unsigned)h) << 16; return v.f;
}

__device__ __forceinline__ void async_copy16(const void* g, void* l) {
  __builtin_amdgcn_global_load_lds(
      (const __attribute__((address_space(1))) void*)g,
      (__attribute__((address_space(3))) void*)l, 16, 0, 0);
}

// ---------------- plain bf16 core: C[M,N] += A[M,K] * B[N,K]^T ----------------
__device__ __forceinline__ void gemm_bt_core(
    const short* __restrict__ A, const short* __restrict__ B,
    int lda, int ldb, int kIters, int blockM, int blockN,
    short (*As)[32], short (*Bs)[32], floatx4 (&acc)[4][4])
{
  const int tid  = threadIdx.x;
  const int lane = tid & 63;
  const int wave = tid >> 6;
  const int wm = (wave >> 1) * 64;
  const int wn = (wave & 1) * 64;
  const int fm = lane & 15;
  const int fk = (lane >> 4) * 8;
  const int r0 = tid >> 2;
  const int c0 = (tid & 3) * 8;

  floatx4 zero = {0.f, 0.f, 0.f, 0.f};
  #pragma unroll
  for (int i = 0; i < 4; ++i)
    #pragma unroll
    for (int j = 0; j < 4; ++j)
      acc[i][j] = zero;

  const short* a0 = A + (size_t)(blockM + r0) * lda + c0;
  const short* a1 = a0 + (size_t)64 * lda;
  const short* b0 = B + (size_t)(blockN + r0) * ldb + c0;
  const short* b1 = b0 + (size_t)64 * ldb;
  short* as0 = &As[r0][c0];
  short* as1 = &As[r0 + 64][c0];
  short* bs0 = &Bs[r0][c0];
  short* bs1 = &Bs[r0 + 64][c0];

  for (int kt = 0; kt < kIters; ++kt) {
    const int kb = kt * 32;
    async_copy16(a0 + kb, as0);
    async_copy16(a1 + kb, as1);
    async_copy16(b0 + kb, bs0);
    async_copy16(b1 + kb, bs1);
    __syncthreads();
    bf16x8 af[4], bfr[4];
    #pragma unroll
    for (int i = 0; i < 4; ++i)
      af[i] = *(const bf16x8*)(&As[wm + i * 16 + fm][fk]);
    #pragma unroll
    for (int j = 0; j < 4; ++j)
      bfr[j] = *(const bf16x8*)(&Bs[wn + j * 16 + fm][fk]);
    #pragma unroll
    for (int i = 0; i < 4; ++i)
      #pragma unroll
      for (int j = 0; j < 4; ++j)
        acc[i][j] = __builtin_amdgcn_mfma_f32_16x16x32_bf16(af[i], bfr[j], acc[i][j], 0, 0, 0);
    __syncthreads();
  }
}

// ---------------- split core: acc += (Ah+Al)*(Bh+Bl)^T via hh+hl+lh ----------------
__device__ __forceinline__ void gemm_bt_split_core(
    const short* __restrict__ Ah, const short* __restrict__ Al,
    const short* __restrict__ Bh, const short* __restrict__ Bl,
    int lda, int ldb, int kIters, int blockM, int blockN,
    short (*AsH)[32], short (*AsL)[32], short (*BsH)[32], short (*BsL)[32],
    floatx4 (&acc)[4][4])
{
  const int tid  = threadIdx.x;
  const int lane = tid & 63;
  const int wave = tid >> 6;
  const int wm = (wave >> 1) * 64;
  const int wn = (wave & 1) * 64;
  const int fm = lane & 15;
  const int fk = (lane >> 4) * 8;
  const int r0 = tid >> 2;
  const int c0 = (tid & 3) * 8;

  floatx4 zero = {0.f, 0.f, 0.f, 0.f};
  #pragma unroll
  for (int i = 0; i < 4; ++i)
    #pragma unroll
    for (int j = 0; j < 4; ++j)
      acc[i][j] = zero;

  const size_t oa0 = (size_t)(blockM + r0) * lda + c0;
  const size_t oa1 = oa0 + (size_t)64 * lda;
  const size_t ob0 = (size_t)(blockN + r0) * ldb + c0;
  const size_t ob1 = ob0 + (size_t)64 * ldb;
  short* lah0 = &AsH[r0][c0]; short* lah1 = &AsH[r0 + 64][c0];
  short* lal0 = &AsL[r0][c0]; short* lal1 = &AsL[r0 + 64][c0];
  short* lbh0 = &BsH[r0][c0]; short* lbh1 = &BsH[r0 + 64][c0];
  short* lbl0 = &BsL[r0][c0]; short* lbl1 = &BsL[r0 + 64][c0];

  for (int kt = 0; kt < kIters; ++kt) {
    const int kb = kt * 32;
    async_copy16(Ah + oa0 + kb, lah0);
    async_copy16(Ah + oa1 + kb, lah1);
    async_copy16(Al + oa0 + kb, lal0);
    async_copy16(Al + oa1 + kb, lal1);
    async_copy16(Bh + ob0 + kb, lbh0);
    async_copy16(Bh + ob1 + kb, lbh1);
    async_copy16(Bl + ob0 + kb, lbl0);
    async_copy16(Bl + ob1 + kb, lbl1);
    __syncthreads();
    bf16x8 ah[4], al[4], bh[4], bl[4];
    #pragma unroll
    for (int i = 0; i < 4; ++i) {
      ah[i] = *(const bf16x8*)(&AsH[wm + i * 16 + fm][fk]);
      al[i] = *(const bf16x8*)(&AsL[wm + i * 16 + fm][fk]);
    }
    #pragma unroll
    for (int j = 0; j < 4; ++j) {
      bh[j] = *(const bf16x8*)(&BsH[wn + j * 16 + fm][fk]);
      bl[j] = *(const bf16x8*)(&BsL[wn + j * 16 + fm][fk]);
    }
    #pragma unroll
    for (int i = 0; i < 4; ++i)
      #pragma unroll
      for (int j = 0; j < 4; ++j) {
        acc[i][j] = __builtin_amdgcn_mfma_f32_16x16x32_bf16(ah[i], bh[j], acc[i][j], 0, 0, 0);
        acc[i][j] = __builtin_amdgcn_mfma_f32_16x16x32_bf16(ah[i], bl[j], acc[i][j], 0, 0, 0);
        acc[i][j] = __builtin_amdgcn_mfma_f32_16x16x32_bf16(al[i], bh[j], acc[i][j], 0, 0, 0);
      }
    __syncthreads();
  }
}

// ---------------- conversions ----------------
// [0,4096): x -> hi/lo split. [4096,4608): Wq split (ORIGINAL layout).
// [4608,5120): Wk split (ORIGINAL layout). [5120,6144): Wv transpose (hi only).

__global__ __launch_bounds__(256) void k_cvt(
    const float4* __restrict__ x,
    const float* __restrict__ wq, const float* __restrict__ wk,
    const float* __restrict__ wv,
    short* __restrict__ xh, short* __restrict__ xl,
    short* __restrict__ wqh, short* __restrict__ wql,
    short* __restrict__ wkh, short* __restrict__ wkl,
    short* __restrict__ wvt)
{
  const int bid = blockIdx.x;
  const int tid = threadIdx.x;
  if (bid < 5120) {
    const float4* src;
    short *dh, *dl;
    size_t idx;
    if (bid < 4096) {
      idx = (size_t)bid * 256 + tid;
      src = x; dh = xh; dl = xl;
    } else if (bid < 4608) {
      idx = (size_t)(bid - 4096) * 256 + tid;
      src = (const float4*)wq; dh = wqh; dl = wql;
    } else {
      idx = (size_t)(bid - 4608) * 256 + tid;
      src = (const float4*)wk; dh = wkh; dl = wkl;
    }
    const float4 u4 = src[idx * 2];
    const float4 w4 = src[idx * 2 + 1];
    float f[8] = {u4.x, u4.y, u4.z, u4.w, w4.x, w4.y, w4.z, w4.w};
    short8v oh, ol;
    #pragma unroll
    for (int e = 0; e < 8; ++e) {
      const unsigned short h = f2bf(f[e]);
      oh[e] = (short)h;
      ol[e] = (short)f2bf(f[e] - bf2f(h));
    }
    *(short8v*)(dh + idx * 8) = oh;
    *(short8v*)(dl + idx * 8) = ol;
  } else {
    const int rem = bid - 5120;
    const int bx = rem & 31, by = rem >> 5;
    const int tx = tid & 31, ty = tid >> 5;  // 32 x 8
    __shared__ float tile[32][33];
    const int colIn = bx * 32 + tx;
    #pragma unroll
    for (int i = 0; i < 4; ++i) {
      const int rowIn = by * 32 + ty + i * 8;
      tile[ty + i * 8][tx] = wv[(size_t)rowIn * D_DIM + colIn];
    }
    __syncthreads();
    const int colOut = by * 32 + tx;   // d (input row of Wv)
    #pragma unroll
    for (int i = 0; i < 4; ++i) {
      const int rowOut = bx * 32 + ty + i * 8;  // n (output col of Wv)
      wvt[(size_t)rowOut * D_DIM + colOut] = (short)f2bf(tile[tx][ty + i * 8]);
    }
  }
}

// ---------------- M^T: mt[e][d] = M[d,e] = sum_i Wq[d,i] Wk[e,i] ----------------
// bt-core with A = Wk (rows e, inner i), B = Wq (rows d, inner i).

__global__ __launch_bounds__(256) void k_gemm_m(
    const short* __restrict__ wqh, const short* __restrict__ wql,
    const short* __restrict__ wkh, const short* __restrict__ wkl,
    short* __restrict__ mth, short* __restrict__ mtl)
{
  __shared__ alignas(16) short AsH[128][32];
  __shared__ alignas(16) short AsL[128][32];
  __shared__ alignas(16) short BsH[128][32];
  __shared__ alignas(16) short BsL[128][32];
  floatx4 acc[4][4];
  const int blockM = blockIdx.y * 128;   // e
  const int blockN = blockIdx.x * 128;   // d
  gemm_bt_split_core(wkh, wkl, wqh, wql,
                     D_DIM, D_DIM, D_DIM / 32, blockM, blockN,
                     AsH, AsL, BsH, BsL, acc);

  const int tid = threadIdx.x, lane = tid & 63, wave = tid >> 6;
  const int wm = (wave >> 1) * 64, wn = (wave & 1) * 64;
  const int rb = wm + ((lane >> 4) << 2);
  const int cb = wn + (lane & 15);
  #pragma unroll
  for (int i = 0; i < 4; ++i)
    #pragma unroll
    for (int j = 0; j < 4; ++j) {
      const int n = blockN + cb + j * 16;
      #pragma unroll
      for (int r = 0; r < 4; ++r) {
        const int m = blockM + rb + i * 16 + r;
        const float f = acc[i][j][r];
        const unsigned short h = f2bf(f);
        mth[(size_t)m * D_DIM + n] = (short)h;
        mtl[(size_t)m * D_DIM + n] = (short)f2bf(f - bf2f(h));
      }
    }
}

// ---------------- mu[e] = mean_d M[d,e] = row-mean of mt row e ----------------

__global__ __launch_bounds__(256) void k_mu(const short* __restrict__ mth,
                                            const short* __restrict__ mtl,
                                            float* __restrict__ mu) {
  const int j = blockIdx.x, tid = threadIdx.x;
  const ushort4 h = *(const ushort4*)(mth + (size_t)j * D_DIM + tid * 4);
  const ushort4 l = *(const ushort4*)(mtl + (size_t)j * D_DIM + tid * 4);
  float s = bf2f(h.x) + bf2f(l.x) + bf2f(h.y) + bf2f(l.y)
          + bf2f(h.z) + bf2f(l.z) + bf2f(h.w) + bf2f(l.w);
  #pragma unroll
  for (int off = 32; off > 0; off >>= 1) s += __shfl_xor(s, off);
  __shared__ float ps[4];
  if ((tid & 63) == 0) ps[tid >> 6] = s;
  __syncthreads();
  if (tid == 0) mu[j] = (ps[0] + ps[1] + ps[2] + ps[3]) * (1.0f / 1024.0f);
}

// ---------------- per-row stats over reconstructed split-x ----------------

__global__ __launch_bounds__(256) void k_rowstats(
    const short* __restrict__ xh, const short* __restrict__ xl,
    const float* __restrict__ mu, float* __restrict__ sq, float* __restrict__ u)
{
  const int r = blockIdx.x, tid = threadIdx.x;
  const ushort4 h = *(const ushort4*)(xh + (size_t)r * D_DIM + tid * 4);
  const ushort4 l = *(const ushort4*)(xl + (size_t)r * D_DIM + tid * 4);
  const float4 m4 = *(const float4*)(mu + tid * 4);
  const float x0 = bf2f(h.x) + bf2f(l.x);
  const float x1 = bf2f(h.y) + bf2f(l.y);
  const float x2 = bf2f(h.z) + bf2f(l.z);
  const float x3 = bf2f(h.w) + bf2f(l.w);
  float s = x0 + x1 + x2 + x3;
  float uu = m4.x * x0 + m4.y * x1 + m4.z * x2 + m4.w * x3;
  #pragma unroll
  for (int off = 32; off > 0; off >>= 1) {
    s  += __shfl_xor(s, off);
    uu += __shfl_xor(uu, off);
  }
  __shared__ float ps[4], pu[4];
  if ((tid & 63) == 0) { ps[tid >> 6] = s; pu[tid >> 6] = uu; }
  __syncthreads();
  if (tid == 0) {
    sq[r] = ps[0] + ps[1] + ps[2] + ps[3];
    u[r]  = pu[0] + pu[1] + pu[2] + pu[3];
  }
}

// ---------------- N~ = x M - sq mu^T, split hi/lo ----------------

__global__ __launch_bounds__(256) void k_gemm_n(
    const short* __restrict__ xh, const short* __restrict__ xl,
    const short* __restrict__ mth, const short* __restrict__ mtl,
    const float* __restrict__ sq, const float* __restrict__ mu,
    short* __restrict__ nh, short* __restrict__ nl)
{
  __shared__ alignas(16) short AsH[128][32];
  __shared__ alignas(16) short AsL[128][32];
  __shared__ alignas(16) short BsH[128][32];
  __shared__ alignas(16) short BsL[128][32];
  floatx4 acc[4][4];
  const int blockM = blockIdx.y * 128;   // global row (b,s)
  const int blockN = blockIdx.x * 128;   // e
  gemm_bt_split_core(xh, xl, mth, mtl, D_DIM, D_DIM, D_DIM / 32,
                     blockM, blockN, AsH, AsL, BsH, BsL, acc);

  const int tid = threadIdx.x, lane = tid & 63, wave = tid >> 6;
  const int wm = (wave >> 1) * 64, wn = (wave & 1) * 64;
  const int rb = wm + ((lane >> 4) << 2);
  const int cb = wn + (lane & 15);
  #pragma unroll
  for (int i = 0; i < 4; ++i)
    #pragma unroll
    for (int j = 0; j < 4; ++j) {
      const int n = blockN + cb + j * 16;
      const float muv = mu[n];
      #pragma unroll
      for (int r = 0; r < 4; ++r) {
        const int m = blockM + rb + i * 16 + r;
        const float f = acc[i][j][r] - sq[m] * muv;   // deflate
        const unsigned short h = f2bf(f);
        nh[(size_t)m * D_DIM + n] = (short)h;
        nl[(size_t)m * D_DIM + n] = (short)f2bf(f - bf2f(h));
      }
    }
}

// ---------------- fused scores (lower-tri, split) + V projection (plain) ----------------

__global__ __launch_bounds__(256) void k_gemm_sv(
    const short* __restrict__ nh, const short* __restrict__ nl,
    const short* __restrict__ xh, const short* __restrict__ xl,
    const float* __restrict__ sq, const float* __restrict__ u,
    const short* __restrict__ wvt, float* __restrict__ attn,
    short* __restrict__ vt)
{
  __shared__ alignas(16) short AsH[128][32];
  __shared__ alignas(16) short AsL[128][32];
  __shared__ alignas(16) short BsH[128][32];
  __shared__ alignas(16) short BsL[128][32];
  floatx4 acc[4][4];
  const int bid = blockIdx.x;
  const int tid = threadIdx.x, lane = tid & 63, wave = tid >> 6;
  const int wm = (wave >> 1) * 64, wn = (wave & 1) * 64;
  const int rb = wm + ((lane >> 4) << 2);
  const int cb = wn + (lane & 15);

  if (bid < 544) {
    const int b = bid / 136;
    int t = bid - b * 136, bi = 0;
    while (t >= bi + 1) { t -= bi + 1; ++bi; }
    const int bj = t;
    const size_t boff = (size_t)b * S_LEN * D_DIM;
    gemm_bt_split_core(nh + boff, nl + boff, xh + boff, xl + boff,
                       D_DIM, D_DIM, D_DIM / 32, bi * 128, bj * 128,
                       AsH, AsL, BsH, BsL, acc);

    float* out = attn + (size_t)b * S_LEN * S_LEN;
    const int rowBase = (b << 11) + bi * 128;   // global q row
    const int colBase = (b << 11) + bj * 128;   // global k row
    #pragma unroll
    for (int j = 0; j < 4; ++j) {
      const int n = bj * 128 + cb + j * 16;
      const float uv = u[colBase + cb + j * 16];
      #pragma unroll
      for (int i = 0; i < 4; ++i)
        #pragma unroll
        for (int r = 0; r < 4; ++r) {
          const int m = bi * 128 + rb + i * 16 + r;
          const float sv = sq[rowBase + rb + i * 16 + r];
          out[(size_t)m * S_LEN + n] = acc[i][j][r] + sv * uv;  // raw scores
        }
    }
  } else {
    const int vb = bid - 544;
    const int blockM = (vb >> 3) * 128;   // global row over 8192
    const int blockN = (vb & 7) * 128;    // d
    gemm_bt_core(xh, wvt, D_DIM, D_DIM, D_DIM / 32, blockM, blockN,
                 AsH, BsH, acc);
    #pragma unroll
    for (int i = 0; i < 4; ++i)
      #pragma unroll
      for (int j = 0; j < 4; ++j) {
        const int n = blockN + cb + j * 16;   // d index
        const int m0 = blockM + rb + i * 16;  // global row, 4-aligned
        const int b = m0 >> 11;
        const int s0 = m0 & (S_LEN - 1);
        ushort4 pk;
        pk.x = f2bf(acc[i][j][0]); pk.y = f2bf(acc[i][j][1]);
        pk.z = f2bf(acc[i][j][2]); pk.w = f2bf(acc[i][j][3]);
        *(ushort4*)(vt + ((size_t)b * D_DIM + n) * S_LEN + s0) = pk;
      }
  }
}

// ---------------- softmax (mask k>q, scale 1/32, write f32 + bf16 P) ----------------

__global__ __launch_bounds__(256) void k_softmax(float* __restrict__ attn,
                                                 short* __restrict__ pb) {
  const int b = blockIdx.x >> 11;
  const int q = blockIdx.x & (S_LEN - 1);
  float* row  = attn + ((size_t)b * S_LEN + q) * S_LEN;
  short* prow = pb   + ((size_t)b * S_LEN + q) * S_LEN;
  const int tid = threadIdx.x;
  __shared__ float sMax[4], sSum[4];
  float v[8];
  float mx = -3.0e38f;
  #pragma unroll
  for (int e = 0; e < 8; ++e) {
    const int k = e * 256 + tid;
    v[e] = (k <= q) ? row[k] : -3.0e38f;   // masked entries never read
    mx = fmaxf(mx, v[e]);
  }
  #pragma unroll
  for (int off = 32; off > 0; off >>= 1) mx = fmaxf(mx, __shfl_xor(mx, off));
  if ((tid & 63) == 0) sMax[tid >> 6] = mx;
  __syncthreads();
  mx = fmaxf(fmaxf(sMax[0], sMax[1]), fmaxf(sMax[2], sMax[3]));

  float s = 0.f;
  #pragma unroll
  for (int e = 0; e < 8; ++e) {
    const int k = e * 256 + tid;
    const float p = (k <= q) ? __expf((v[e] - mx) * 0.03125f) : 0.f;  // 1/sqrt(1024)
    v[e] = p;
    s += p;
  }
  #pragma unroll
  for (int off = 32; off > 0; off >>= 1) s += __shfl_xor(s, off);
  if ((tid & 63) == 0) sSum[tid >> 6] = s;
  __syncthreads();
  s = sSum[0] + sSum[1] + sSum[2] + sSum[3];
  const float inv = 1.0f / s;

  #pragma unroll
  for (int e = 0; e < 8; ++e) {
    const int k = e * 256 + tid;
    const float o = v[e] * inv;            // 0 for masked
    row[k] = o;
    prow[k] = (short)f2bf(o);
  }
}

// ---------------- context = P @ V, K truncated; heavy block-rows first ----------------

__global__ __launch_bounds__(256) void k_gemm_ctx(
    const short* __restrict__ pb, const short* __restrict__ vt,
    float* __restrict__ ctx)
{
  __shared__ alignas(16) short As[128][32];
  __shared__ alignas(16) short Bs[128][32];
  floatx4 acc[4][4];
  const int b = blockIdx.z;
  const int by = 15 - blockIdx.y;        // reversed: heavy K-loops first
  const int blockM = by * 128;           // q
  const int blockN = blockIdx.x * 128;   // d
  const int kIters = by * 4 + 4;         // k <= blockM+127 only
  const short* A = pb + (size_t)b * S_LEN * S_LEN;
  const short* B = vt + (size_t)b * D_DIM * S_LEN;
  gemm_bt_core(A, B, S_LEN, S_LEN, kIters, blockM, blockN, As, Bs, acc);

  float* out = ctx + (size_t)b * S_LEN * D_DIM;
  const int tid = threadIdx.x, lane = tid & 63, wave = tid >> 6;
  const int wm = (wave >> 1) * 64, wn = (wave & 1) * 64;
  const int rb = wm + ((lane >> 4) << 2);
  const int cb = wn + (lane & 15);
  #pragma unroll
  for (int i = 0; i < 4; ++i)
    #pragma unroll
    for (int j = 0; j < 4; ++j) {
      const int n = blockN + cb + j * 16;
      #pragma unroll
      for (int r = 0; r < 4; ++r) {
        const int m = blockM + rb + i * 16 + r;
        out[(size_t)m * D_DIM + n] = acc[i][j][r];
      }
    }
}

// ---------------- launch ----------------

extern "C" void kernel_launch(void* const* d_in, const int* in_sizes, int n_in,
                              void* d_out, int out_size, void* d_ws, size_t ws_size,
                              hipStream_t stream) {
  const float* x  = (const float*)d_in[0];
  const float* wq = (const float*)d_in[1];
  const float* wk = (const float*)d_in[2];
  const float* wv = (const float*)d_in[3];

  float* out  = (float*)d_out;
  float* ctx  = out;                                       // [4,2048,1024]
  float* attn = out + (size_t)NBATCH * S_LEN * D_DIM;      // [4,2048,2048]

  // workspace (shorts), ~94 MiB; pb aliases nh/nl (dead after scores GEMM)
  short* ws  = (short*)d_ws;
  short* xh  = ws;                                  // 8M
  short* xl  = xh + (size_t)8 * MEG;                // 8M
  short* wqh = xl + (size_t)8 * MEG;                // 1M Wq hi (original layout)
  short* wql = wqh + (size_t)1 * MEG;               // 1M Wq lo
  short* wkh = wql + (size_t)1 * MEG;               // 1M Wk hi
  short* wkl = wkh + (size_t)1 * MEG;               // 1M Wk lo
  short* wvt = wkl + (size_t)1 * MEG;               // 1M Wv^T hi
  short* mth = wvt + (size_t)1 * MEG;               // 1M M^T hi
  short* mtl = mth + (size_t)1 * MEG;               // 1M M^T lo
  short* nh  = mtl + (size_t)1 * MEG;               // 8M N~ hi
  short* nl  = nh + (size_t)8 * MEG;                // 8M N~ lo
  short* vt  = nl + (size_t)8 * MEG;                // 8M V^T [b,d,s]
  short* pb  = nh;                                  // 16M alias (nh+nl)
  float* fb  = (float*)(vt + (size_t)8 * MEG);
  float* mu  = fb;                                  // 1024
  float* sq  = fb + 1024;                           // 8192
  float* u   = sq + 8192;                           // 8192

  k_cvt<<<6144, 256, 0, stream>>>((const float4*)x, wq, wk, wv,
                                  xh, xl, wqh, wql, wkh, wkl, wvt);
  k_gemm_m<<<dim3(8, 8), 256, 0, stream>>>(wqh, wql, wkh, wkl, mth, mtl);
  k_mu<<<1024, 256, 0, stream>>>(mth, mtl, mu);
  k_rowstats<<<8192, 256, 0, stream>>>(xh, xl, mu, sq, u);
  k_gemm_n<<<dim3(8, 64), 256, 0, stream>>>(xh, xl, mth, mtl, sq, mu, nh, nl);
  k_gemm_sv<<<1056, 256, 0, stream>>>(nh, nl, xh, xl, sq, u, wvt, attn, vt);
  k_softmax<<<NBATCH * S_LEN, 256, 0, stream>>>(attn, pb);
  k_gemm_ctx<<<dim3(8, 16, 4), 256, 0, stream>>>(pb, vt, ctx);
}

// Round 5
// 399.293 us; speedup vs baseline: 1.1063x; 1.0790x over previous
//
#include <hip/hip_runtime.h>
#include <cstdint>
#include <cstddef>

// CausalAttention B=4 S=2048 D=1024.
// d_out = [context (4*2048*1024 f32)] ++ [attn_scores (4*2048*2048 f32)]
//
// scores = x M x^T, M[d,e] = sum_i Wq[d,i] Wk[e,i]:
//   M^T = bt(A=Wk, B=Wq)      (split bf16 3-pass)
//   N~  = x M - sq*mu^T       (split; mean-deflated)
//   S   = N~ x^T + sq*u       (split, lower-tri; exact f32 rank-1 add-back)
// Round-5: k_gemm_sv was fetch-latency bound (MfmaUtil 23%, HBM 40%,
// FETCH 342 MB — 64 MB working set thrashing per-XCD L2 under the m97
// vmcnt(0) barrier). Rebuilt as 256x256-tile / 512-thread core (2x MFMA
// per barrier per copy) + persistent-block work stealing (512 blocks =
// exactly 2/CU at 64 KB LDS) over 144 score + 128 V items.

#define S_LEN 2048
#define D_DIM 1024
#define NBATCH 4
#define MEG (1024 * 1024)
#define SV_ITEMS 272   // 144 score (4 batches x 36 lower-tri 256-tiles) + 128 V

typedef __attribute__((ext_vector_type(4))) float floatx4;
typedef __attribute__((ext_vector_type(8))) __bf16 bf16x8;
typedef __attribute__((ext_vector_type(8))) short short8v;

__device__ __forceinline__ unsigned short f2bf(float f) {
  union { float f; unsigned u; } v; v.f = f;
  unsigned r = v.u + 0x7FFF + ((v.u >> 16) & 1);   // round-to-nearest-even
  return (unsigned short)(r >> 16);
}
__device__ __forceinline__ float bf2f(unsigned short h) {
  union { unsigned u; float f; } v; v.u = ((unsigned)h) << 16; return v.f;
}

__device__ __forceinline__ void async_copy16(const void* g, void* l) {
  __builtin_amdgcn_global_load_lds(
      (const __attribute__((address_space(1))) void*)g,
      (__attribute__((address_space(3))) void*)l, 16, 0, 0);
}

// ================= 256-thread, 128x128-tile cores (m, n, ctx) =================

__device__ __forceinline__ void gemm_bt_core(
    const short* __restrict__ A, const short* __restrict__ B,
    int lda, int ldb, int kIters, int blockM, int blockN,
    short (*As)[32], short (*Bs)[32], floatx4 (&acc)[4][4])
{
  const int tid  = threadIdx.x;
  const int lane = tid & 63;
  const int wave = tid >> 6;
  const int wm = (wave >> 1) * 64;
  const int wn = (wave & 1) * 64;
  const int fm = lane & 15;
  const int fk = (lane >> 4) * 8;
  const int r0 = tid >> 2;
  const int c0 = (tid & 3) * 8;

  floatx4 zero = {0.f, 0.f, 0.f, 0.f};
  #pragma unroll
  for (int i = 0; i < 4; ++i)
    #pragma unroll
    for (int j = 0; j < 4; ++j)
      acc[i][j] = zero;

  const short* a0 = A + (size_t)(blockM + r0) * lda + c0;
  const short* a1 = a0 + (size_t)64 * lda;
  const short* b0 = B + (size_t)(blockN + r0) * ldb + c0;
  const short* b1 = b0 + (size_t)64 * ldb;
  short* as0 = &As[r0][c0];
  short* as1 = &As[r0 + 64][c0];
  short* bs0 = &Bs[r0][c0];
  short* bs1 = &Bs[r0 + 64][c0];

  for (int kt = 0; kt < kIters; ++kt) {
    const int kb = kt * 32;
    async_copy16(a0 + kb, as0);
    async_copy16(a1 + kb, as1);
    async_copy16(b0 + kb, bs0);
    async_copy16(b1 + kb, bs1);
    __syncthreads();
    bf16x8 af[4], bfr[4];
    #pragma unroll
    for (int i = 0; i < 4; ++i)
      af[i] = *(const bf16x8*)(&As[wm + i * 16 + fm][fk]);
    #pragma unroll
    for (int j = 0; j < 4; ++j)
      bfr[j] = *(const bf16x8*)(&Bs[wn + j * 16 + fm][fk]);
    #pragma unroll
    for (int i = 0; i < 4; ++i)
      #pragma unroll
      for (int j = 0; j < 4; ++j)
        acc[i][j] = __builtin_amdgcn_mfma_f32_16x16x32_bf16(af[i], bfr[j], acc[i][j], 0, 0, 0);
    __syncthreads();
  }
}

__device__ __forceinline__ void gemm_bt_split_core(
    const short* __restrict__ Ah, const short* __restrict__ Al,
    const short* __restrict__ Bh, const short* __restrict__ Bl,
    int lda, int ldb, int kIters, int blockM, int blockN,
    short (*AsH)[32], short (*AsL)[32], short (*BsH)[32], short (*BsL)[32],
    floatx4 (&acc)[4][4])
{
  const int tid  = threadIdx.x;
  const int lane = tid & 63;
  const int wave = tid >> 6;
  const int wm = (wave >> 1) * 64;
  const int wn = (wave & 1) * 64;
  const int fm = lane & 15;
  const int fk = (lane >> 4) * 8;
  const int r0 = tid >> 2;
  const int c0 = (tid & 3) * 8;

  floatx4 zero = {0.f, 0.f, 0.f, 0.f};
  #pragma unroll
  for (int i = 0; i < 4; ++i)
    #pragma unroll
    for (int j = 0; j < 4; ++j)
      acc[i][j] = zero;

  const size_t oa0 = (size_t)(blockM + r0) * lda + c0;
  const size_t oa1 = oa0 + (size_t)64 * lda;
  const size_t ob0 = (size_t)(blockN + r0) * ldb + c0;
  const size_t ob1 = ob0 + (size_t)64 * ldb;
  short* lah0 = &AsH[r0][c0]; short* lah1 = &AsH[r0 + 64][c0];
  short* lal0 = &AsL[r0][c0]; short* lal1 = &AsL[r0 + 64][c0];
  short* lbh0 = &BsH[r0][c0]; short* lbh1 = &BsH[r0 + 64][c0];
  short* lbl0 = &BsL[r0][c0]; short* lbl1 = &BsL[r0 + 64][c0];

  for (int kt = 0; kt < kIters; ++kt) {
    const int kb = kt * 32;
    async_copy16(Ah + oa0 + kb, lah0);
    async_copy16(Ah + oa1 + kb, lah1);
    async_copy16(Al + oa0 + kb, lal0);
    async_copy16(Al + oa1 + kb, lal1);
    async_copy16(Bh + ob0 + kb, lbh0);
    async_copy16(Bh + ob1 + kb, lbh1);
    async_copy16(Bl + ob0 + kb, lbl0);
    async_copy16(Bl + ob1 + kb, lbl1);
    __syncthreads();
    bf16x8 ah[4], al[4], bh[4], bl[4];
    #pragma unroll
    for (int i = 0; i < 4; ++i) {
      ah[i] = *(const bf16x8*)(&AsH[wm + i * 16 + fm][fk]);
      al[i] = *(const bf16x8*)(&AsL[wm + i * 16 + fm][fk]);
    }
    #pragma unroll
    for (int j = 0; j < 4; ++j) {
      bh[j] = *(const bf16x8*)(&BsH[wn + j * 16 + fm][fk]);
      bl[j] = *(const bf16x8*)(&BsL[wn + j * 16 + fm][fk]);
    }
    #pragma unroll
    for (int i = 0; i < 4; ++i)
      #pragma unroll
      for (int j = 0; j < 4; ++j) {
        acc[i][j] = __builtin_amdgcn_mfma_f32_16x16x32_bf16(ah[i], bh[j], acc[i][j], 0, 0, 0);
        acc[i][j] = __builtin_amdgcn_mfma_f32_16x16x32_bf16(ah[i], bl[j], acc[i][j], 0, 0, 0);
        acc[i][j] = __builtin_amdgcn_mfma_f32_16x16x32_bf16(al[i], bh[j], acc[i][j], 0, 0, 0);
      }
    __syncthreads();
  }
}

// ================= 512-thread, 256x256-tile cores (sv only) =================
// 8 waves as 4x2: wave tile 64 rows x 128 cols, acc[4][8].

__device__ __forceinline__ void gemm_bt_core512(
    const short* __restrict__ A, const short* __restrict__ B,
    int lda, int ldb, int kIters, int blockM, int blockN,
    short (*As)[32], short (*Bs)[32], floatx4 (&acc)[4][8])
{
  const int tid  = threadIdx.x;
  const int lane = tid & 63;
  const int wave = tid >> 6;
  const int wm = (wave >> 1) * 64;     // 0,64,128,192
  const int wn = (wave & 1) * 128;     // 0,128
  const int fm = lane & 15;
  const int fk = (lane >> 4) * 8;
  const int r0 = tid >> 2;             // 0..127
  const int c0 = (tid & 3) * 8;

  floatx4 zero = {0.f, 0.f, 0.f, 0.f};
  #pragma unroll
  for (int i = 0; i < 4; ++i)
    #pragma unroll
    for (int j = 0; j < 8; ++j)
      acc[i][j] = zero;

  const short* a0 = A + (size_t)(blockM + r0) * lda + c0;
  const short* a1 = a0 + (size_t)128 * lda;
  const short* b0 = B + (size_t)(blockN + r0) * ldb + c0;
  const short* b1 = b0 + (size_t)128 * ldb;
  short* as0 = &As[r0][c0];
  short* as1 = &As[r0 + 128][c0];
  short* bs0 = &Bs[r0][c0];
  short* bs1 = &Bs[r0 + 128][c0];

  for (int kt = 0; kt < kIters; ++kt) {
    const int kb = kt * 32;
    async_copy16(a0 + kb, as0);
    async_copy16(a1 + kb, as1);
    async_copy16(b0 + kb, bs0);
    async_copy16(b1 + kb, bs1);
    __syncthreads();
    bf16x8 af[4], bfr[8];
    #pragma unroll
    for (int i = 0; i < 4; ++i)
      af[i] = *(const bf16x8*)(&As[wm + i * 16 + fm][fk]);
    #pragma unroll
    for (int j = 0; j < 8; ++j)
      bfr[j] = *(const bf16x8*)(&Bs[wn + j * 16 + fm][fk]);
    #pragma unroll
    for (int i = 0; i < 4; ++i)
      #pragma unroll
      for (int j = 0; j < 8; ++j)
        acc[i][j] = __builtin_amdgcn_mfma_f32_16x16x32_bf16(af[i], bfr[j], acc[i][j], 0, 0, 0);
    __syncthreads();
  }
}

__device__ __forceinline__ void gemm_bt_split_core512(
    const short* __restrict__ Ah, const short* __restrict__ Al,
    const short* __restrict__ Bh, const short* __restrict__ Bl,
    int lda, int ldb, int kIters, int blockM, int blockN,
    short (*AsH)[32], short (*AsL)[32], short (*BsH)[32], short (*BsL)[32],
    floatx4 (&acc)[4][8])
{
  const int tid  = threadIdx.x;
  const int lane = tid & 63;
  const int wave = tid >> 6;
  const int wm = (wave >> 1) * 64;
  const int wn = (wave & 1) * 128;
  const int fm = lane & 15;
  const int fk = (lane >> 4) * 8;
  const int r0 = tid >> 2;
  const int c0 = (tid & 3) * 8;

  floatx4 zero = {0.f, 0.f, 0.f, 0.f};
  #pragma unroll
  for (int i = 0; i < 4; ++i)
    #pragma unroll
    for (int j = 0; j < 8; ++j)
      acc[i][j] = zero;

  const size_t oa0 = (size_t)(blockM + r0) * lda + c0;
  const size_t oa1 = oa0 + (size_t)128 * lda;
  const size_t ob0 = (size_t)(blockN + r0) * ldb + c0;
  const size_t ob1 = ob0 + (size_t)128 * ldb;
  short* lah0 = &AsH[r0][c0]; short* lah1 = &AsH[r0 + 128][c0];
  short* lal0 = &AsL[r0][c0]; short* lal1 = &AsL[r0 + 128][c0];
  short* lbh0 = &BsH[r0][c0]; short* lbh1 = &BsH[r0 + 128][c0];
  short* lbl0 = &BsL[r0][c0]; short* lbl1 = &BsL[r0 + 128][c0];

  for (int kt = 0; kt < kIters; ++kt) {
    const int kb = kt * 32;
    async_copy16(Ah + oa0 + kb, lah0);
    async_copy16(Ah + oa1 + kb, lah1);
    async_copy16(Al + oa0 + kb, lal0);
    async_copy16(Al + oa1 + kb, lal1);
    async_copy16(Bh + ob0 + kb, lbh0);
    async_copy16(Bh + ob1 + kb, lbh1);
    async_copy16(Bl + ob0 + kb, lbl0);
    async_copy16(Bl + ob1 + kb, lbl1);
    __syncthreads();
    // pass-wise to cap register pressure (acc already costs 128 VGPRs)
    bf16x8 ah[4], bh[8], bl[8];
    #pragma unroll
    for (int i = 0; i < 4; ++i)
      ah[i] = *(const bf16x8*)(&AsH[wm + i * 16 + fm][fk]);
    #pragma unroll
    for (int j = 0; j < 8; ++j)
      bh[j] = *(const bf16x8*)(&BsH[wn + j * 16 + fm][fk]);
    #pragma unroll
    for (int i = 0; i < 4; ++i)
      #pragma unroll
      for (int j = 0; j < 8; ++j)
        acc[i][j] = __builtin_amdgcn_mfma_f32_16x16x32_bf16(ah[i], bh[j], acc[i][j], 0, 0, 0);
    #pragma unroll
    for (int j = 0; j < 8; ++j)
      bl[j] = *(const bf16x8*)(&BsL[wn + j * 16 + fm][fk]);
    #pragma unroll
    for (int i = 0; i < 4; ++i)
      #pragma unroll
      for (int j = 0; j < 8; ++j)
        acc[i][j] = __builtin_amdgcn_mfma_f32_16x16x32_bf16(ah[i], bl[j], acc[i][j], 0, 0, 0);
    #pragma unroll
    for (int i = 0; i < 4; ++i) {
      const bf16x8 al = *(const bf16x8*)(&AsL[wm + i * 16 + fm][fk]);
      #pragma unroll
      for (int j = 0; j < 8; ++j)
        acc[i][j] = __builtin_amdgcn_mfma_f32_16x16x32_bf16(al, bh[j], acc[i][j], 0, 0, 0);
    }
    __syncthreads();
  }
}

// ---------------- conversions ----------------
// [0,4096): x -> hi/lo split. [4096,4608): Wq split (ORIGINAL layout).
// [4608,5120): Wk split (ORIGINAL layout). [5120,6144): Wv transpose (hi only).

__global__ __launch_bounds__(256) void k_cvt(
    const float4* __restrict__ x,
    const float* __restrict__ wq, const float* __restrict__ wk,
    const float* __restrict__ wv,
    short* __restrict__ xh, short* __restrict__ xl,
    short* __restrict__ wqh, short* __restrict__ wql,
    short* __restrict__ wkh, short* __restrict__ wkl,
    short* __restrict__ wvt)
{
  const int bid = blockIdx.x;
  const int tid = threadIdx.x;
  if (bid < 5120) {
    const float4* src;
    short *dh, *dl;
    size_t idx;
    if (bid < 4096) {
      idx = (size_t)bid * 256 + tid;
      src = x; dh = xh; dl = xl;
    } else if (bid < 4608) {
      idx = (size_t)(bid - 4096) * 256 + tid;
      src = (const float4*)wq; dh = wqh; dl = wql;
    } else {
      idx = (size_t)(bid - 4608) * 256 + tid;
      src = (const float4*)wk; dh = wkh; dl = wkl;
    }
    const float4 u4 = src[idx * 2];
    const float4 w4 = src[idx * 2 + 1];
    float f[8] = {u4.x, u4.y, u4.z, u4.w, w4.x, w4.y, w4.z, w4.w};
    short8v oh, ol;
    #pragma unroll
    for (int e = 0; e < 8; ++e) {
      const unsigned short h = f2bf(f[e]);
      oh[e] = (short)h;
      ol[e] = (short)f2bf(f[e] - bf2f(h));
    }
    *(short8v*)(dh + idx * 8) = oh;
    *(short8v*)(dl + idx * 8) = ol;
  } else {
    const int rem = bid - 5120;
    const int bx = rem & 31, by = rem >> 5;
    const int tx = tid & 31, ty = tid >> 5;  // 32 x 8
    __shared__ float tile[32][33];
    const int colIn = bx * 32 + tx;
    #pragma unroll
    for (int i = 0; i < 4; ++i) {
      const int rowIn = by * 32 + ty + i * 8;
      tile[ty + i * 8][tx] = wv[(size_t)rowIn * D_DIM + colIn];
    }
    __syncthreads();
    const int colOut = by * 32 + tx;   // d (input row of Wv)
    #pragma unroll
    for (int i = 0; i < 4; ++i) {
      const int rowOut = bx * 32 + ty + i * 8;  // n (output col of Wv)
      wvt[(size_t)rowOut * D_DIM + colOut] = (short)f2bf(tile[tx][ty + i * 8]);
    }
  }
}

// ---------------- M^T: mt[e][d] = sum_i Wq[d,i] Wk[e,i] ----------------

__global__ __launch_bounds__(256) void k_gemm_m(
    const short* __restrict__ wqh, const short* __restrict__ wql,
    const short* __restrict__ wkh, const short* __restrict__ wkl,
    short* __restrict__ mth, short* __restrict__ mtl)
{
  __shared__ alignas(16) short AsH[128][32];
  __shared__ alignas(16) short AsL[128][32];
  __shared__ alignas(16) short BsH[128][32];
  __shared__ alignas(16) short BsL[128][32];
  floatx4 acc[4][4];
  const int blockM = blockIdx.y * 128;   // e
  const int blockN = blockIdx.x * 128;   // d
  gemm_bt_split_core(wkh, wkl, wqh, wql,
                     D_DIM, D_DIM, D_DIM / 32, blockM, blockN,
                     AsH, AsL, BsH, BsL, acc);

  const int tid = threadIdx.x, lane = tid & 63, wave = tid >> 6;
  const int wm = (wave >> 1) * 64, wn = (wave & 1) * 64;
  const int rb = wm + ((lane >> 4) << 2);
  const int cb = wn + (lane & 15);
  #pragma unroll
  for (int i = 0; i < 4; ++i)
    #pragma unroll
    for (int j = 0; j < 4; ++j) {
      const int n = blockN + cb + j * 16;
      #pragma unroll
      for (int r = 0; r < 4; ++r) {
        const int m = blockM + rb + i * 16 + r;
        const float f = acc[i][j][r];
        const unsigned short h = f2bf(f);
        mth[(size_t)m * D_DIM + n] = (short)h;
        mtl[(size_t)m * D_DIM + n] = (short)f2bf(f - bf2f(h));
      }
    }
}

// ---------------- mu[e] = mean_d M[d,e] ----------------

__global__ __launch_bounds__(256) void k_mu(const short* __restrict__ mth,
                                            const short* __restrict__ mtl,
                                            float* __restrict__ mu) {
  const int j = blockIdx.x, tid = threadIdx.x;
  const ushort4 h = *(const ushort4*)(mth + (size_t)j * D_DIM + tid * 4);
  const ushort4 l = *(const ushort4*)(mtl + (size_t)j * D_DIM + tid * 4);
  float s = bf2f(h.x) + bf2f(l.x) + bf2f(h.y) + bf2f(l.y)
          + bf2f(h.z) + bf2f(l.z) + bf2f(h.w) + bf2f(l.w);
  #pragma unroll
  for (int off = 32; off > 0; off >>= 1) s += __shfl_xor(s, off);
  __shared__ float ps[4];
  if ((tid & 63) == 0) ps[tid >> 6] = s;
  __syncthreads();
  if (tid == 0) mu[j] = (ps[0] + ps[1] + ps[2] + ps[3]) * (1.0f / 1024.0f);
}

// ---------------- per-row stats + sv work-counter init ----------------

__global__ __launch_bounds__(256) void k_rowstats(
    const short* __restrict__ xh, const short* __restrict__ xl,
    const float* __restrict__ mu, float* __restrict__ sq, float* __restrict__ u,
    int* __restrict__ ctr)
{
  const int r = blockIdx.x, tid = threadIdx.x;
  if (r == 0 && tid == 0) *ctr = 0;   // re-init every launch (graph-safe)
  const ushort4 h = *(const ushort4*)(xh + (size_t)r * D_DIM + tid * 4);
  const ushort4 l = *(const ushort4*)(xl + (size_t)r * D_DIM + tid * 4);
  const float4 m4 = *(const float4*)(mu + tid * 4);
  const float x0 = bf2f(h.x) + bf2f(l.x);
  const float x1 = bf2f(h.y) + bf2f(l.y);
  const float x2 = bf2f(h.z) + bf2f(l.z);
  const float x3 = bf2f(h.w) + bf2f(l.w);
  float s = x0 + x1 + x2 + x3;
  float uu = m4.x * x0 + m4.y * x1 + m4.z * x2 + m4.w * x3;
  #pragma unroll
  for (int off = 32; off > 0; off >>= 1) {
    s  += __shfl_xor(s, off);
    uu += __shfl_xor(uu, off);
  }
  __shared__ float ps[4], pu[4];
  if ((tid & 63) == 0) { ps[tid >> 6] = s; pu[tid >> 6] = uu; }
  __syncthreads();
  if (tid == 0) {
    sq[r] = ps[0] + ps[1] + ps[2] + ps[3];
    u[r]  = pu[0] + pu[1] + pu[2] + pu[3];
  }
}

// ---------------- N~ = x M - sq mu^T, split hi/lo (128-tile core) ----------------

__global__ __launch_bounds__(256) void k_gemm_n(
    const short* __restrict__ xh, const short* __restrict__ xl,
    const short* __restrict__ mth, const short* __restrict__ mtl,
    const float* __restrict__ sq, const float* __restrict__ mu,
    short* __restrict__ nh, short* __restrict__ nl)
{
  __shared__ alignas(16) short AsH[128][32];
  __shared__ alignas(16) short AsL[128][32];
  __shared__ alignas(16) short BsH[128][32];
  __shared__ alignas(16) short BsL[128][32];
  floatx4 acc[4][4];
  const int blockM = blockIdx.y * 128;   // global row (b,s)
  const int blockN = blockIdx.x * 128;   // e
  gemm_bt_split_core(xh, xl, mth, mtl, D_DIM, D_DIM, D_DIM / 32,
                     blockM, blockN, AsH, AsL, BsH, BsL, acc);

  const int tid = threadIdx.x, lane = tid & 63, wave = tid >> 6;
  const int wm = (wave >> 1) * 64, wn = (wave & 1) * 64;
  const int rb = wm + ((lane >> 4) << 2);
  const int cb = wn + (lane & 15);
  #pragma unroll
  for (int i = 0; i < 4; ++i)
    #pragma unroll
    for (int j = 0; j < 4; ++j) {
      const int n = blockN + cb + j * 16;
      const float muv = mu[n];
      #pragma unroll
      for (int r = 0; r < 4; ++r) {
        const int m = blockM + rb + i * 16 + r;
        const float f = acc[i][j][r] - sq[m] * muv;   // deflate
        const unsigned short h = f2bf(f);
        nh[(size_t)m * D_DIM + n] = (short)h;
        nl[(size_t)m * D_DIM + n] = (short)f2bf(f - bf2f(h));
      }
    }
}

// ---------------- fused scores + V, 256x256 tiles, work-stealing ----------------
// items [0,144): score tile (b, bi>=bj in 8x8); items [144,272): V 256x256.

__global__ __launch_bounds__(512, 2) void k_gemm_sv512(
    const short* __restrict__ nh, const short* __restrict__ nl,
    const short* __restrict__ xh, const short* __restrict__ xl,
    const float* __restrict__ sq, const float* __restrict__ u,
    const short* __restrict__ wvt, float* __restrict__ attn,
    short* __restrict__ vt, int* __restrict__ ctr)
{
  __shared__ alignas(16) short AsH[256][32];
  __shared__ alignas(16) short AsL[256][32];
  __shared__ alignas(16) short BsH[256][32];
  __shared__ alignas(16) short BsL[256][32];
  __shared__ int s_item;
  floatx4 acc[4][8];

  const int tid = threadIdx.x, lane = tid & 63, wave = tid >> 6;
  const int wm = (wave >> 1) * 64, wn = (wave & 1) * 128;
  const int rb = wm + ((lane >> 4) << 2);
  const int cb = wn + (lane & 15);

  for (;;) {
    if (tid == 0) s_item = atomicAdd(ctr, 1);
    __syncthreads();
    const int it = s_item;
    if (it >= SV_ITEMS) break;

    if (it < 144) {
      const int b = it / 36;
      int t = it - b * 36, bi = 0;
      while (t >= bi + 1) { t -= bi + 1; ++bi; }
      const int bj = t;
      const size_t boff = (size_t)b * S_LEN * D_DIM;
      gemm_bt_split_core512(nh + boff, nl + boff, xh + boff, xl + boff,
                            D_DIM, D_DIM, D_DIM / 32, bi * 256, bj * 256,
                            AsH, AsL, BsH, BsL, acc);

      float* out = attn + (size_t)b * S_LEN * S_LEN;
      const int rowBase = (b << 11) + bi * 256;
      const int colBase = (b << 11) + bj * 256;
      #pragma unroll
      for (int j = 0; j < 8; ++j) {
        const int n = bj * 256 + cb + j * 16;
        const float uv = u[colBase + cb + j * 16];
        #pragma unroll
        for (int i = 0; i < 4; ++i)
          #pragma unroll
          for (int r = 0; r < 4; ++r) {
            const int m = bi * 256 + rb + i * 16 + r;
            const float sv = sq[rowBase + rb + i * 16 + r];
            out[(size_t)m * S_LEN + n] = acc[i][j][r] + sv * uv;  // raw scores
          }
      }
    } else {
      const int vb = it - 144;
      const int blockM = (vb >> 2) * 256;   // global row over 8192
      const int blockN = (vb & 3) * 256;    // d
      gemm_bt_core512(xh, wvt, D_DIM, D_DIM, D_DIM / 32, blockM, blockN,
                      AsH, BsH, acc);
      #pragma unroll
      for (int i = 0; i < 4; ++i)
        #pragma unroll
        for (int j = 0; j < 8; ++j) {
          const int n = blockN + cb + j * 16;   // d index
          const int m0 = blockM + rb + i * 16;  // global row, 4-aligned
          const int b = m0 >> 11;
          const int s0 = m0 & (S_LEN - 1);
          ushort4 pk;
          pk.x = f2bf(acc[i][j][0]); pk.y = f2bf(acc[i][j][1]);
          pk.z = f2bf(acc[i][j][2]); pk.w = f2bf(acc[i][j][3]);
          *(ushort4*)(vt + ((size_t)b * D_DIM + n) * S_LEN + s0) = pk;
        }
    }
  }
}

// ---------------- softmax (mask k>q, scale 1/32, write f32 + bf16 P) ----------------

__global__ __launch_bounds__(256) void k_softmax(float* __restrict__ attn,
                                                 short* __restrict__ pb) {
  const int b = blockIdx.x >> 11;
  const int q = blockIdx.x & (S_LEN - 1);
  float* row  = attn + ((size_t)b * S_LEN + q) * S_LEN;
  short* prow = pb   + ((size_t)b * S_LEN + q) * S_LEN;
  const int tid = threadIdx.x;
  __shared__ float sMax[4], sSum[4];
  float v[8];
  float mx = -3.0e38f;
  #pragma unroll
  for (int e = 0; e < 8; ++e) {
    const int k = e * 256 + tid;
    v[e] = (k <= q) ? row[k] : -3.0e38f;   // masked entries never read
    mx = fmaxf(mx, v[e]);
  }
  #pragma unroll
  for (int off = 32; off > 0; off >>= 1) mx = fmaxf(mx, __shfl_xor(mx, off));
  if ((tid & 63) == 0) sMax[tid >> 6] = mx;
  __syncthreads();
  mx = fmaxf(fmaxf(sMax[0], sMax[1]), fmaxf(sMax[2], sMax[3]));

  float s = 0.f;
  #pragma unroll
  for (int e = 0; e < 8; ++e) {
    const int k = e * 256 + tid;
    const float p = (k <= q) ? __expf((v[e] - mx) * 0.03125f) : 0.f;  // 1/sqrt(1024)
    v[e] = p;
    s += p;
  }
  #pragma unroll
  for (int off = 32; off > 0; off >>= 1) s += __shfl_xor(s, off);
  if ((tid & 63) == 0) sSum[tid >> 6] = s;
  __syncthreads();
  s = sSum[0] + sSum[1] + sSum[2] + sSum[3];
  const float inv = 1.0f / s;

  #pragma unroll
  for (int e = 0; e < 8; ++e) {
    const int k = e * 256 + tid;
    const float o = v[e] * inv;            // 0 for masked
    row[k] = o;
    prow[k] = (short)f2bf(o);
  }
}

// ---------------- context = P @ V, K truncated; heavy block-rows first ----------------

__global__ __launch_bounds__(256) void k_gemm_ctx(
    const short* __restrict__ pb, const short* __restrict__ vt,
    float* __restrict__ ctx)
{
  __shared__ alignas(16) short As[128][32];
  __shared__ alignas(16) short Bs[128][32];
  floatx4 acc[4][4];
  const int b = blockIdx.z;
  const int by = 15 - blockIdx.y;        // reversed: heavy K-loops first
  const int blockM = by * 128;           // q
  const int blockN = blockIdx.x * 128;   // d
  const int kIters = by * 4 + 4;         // k <= blockM+127 only
  const short* A = pb + (size_t)b * S_LEN * S_LEN;
  const short* B = vt + (size_t)b * D_DIM * S_LEN;
  gemm_bt_core(A, B, S_LEN, S_LEN, kIters, blockM, blockN, As, Bs, acc);

  float* out = ctx + (size_t)b * S_LEN * D_DIM;
  const int tid = threadIdx.x, lane = tid & 63, wave = tid >> 6;
  const int wm = (wave >> 1) * 64, wn = (wave & 1) * 64;
  const int rb = wm + ((lane >> 4) << 2);
  const int cb = wn + (lane & 15);
  #pragma unroll
  for (int i = 0; i < 4; ++i)
    #pragma unroll
    for (int j = 0; j < 4; ++j) {
      const int n = blockN + cb + j * 16;
      #pragma unroll
      for (int r = 0; r < 4; ++r) {
        const int m = blockM + rb + i * 16 + r;
        out[(size_t)m * D_DIM + n] = acc[i][j][r];
      }
    }
}

// ---------------- launch ----------------

extern "C" void kernel_launch(void* const* d_in, const int* in_sizes, int n_in,
                              void* d_out, int out_size, void* d_ws, size_t ws_size,
                              hipStream_t stream) {
  const float* x  = (const float*)d_in[0];
  const float* wq = (const float*)d_in[1];
  const float* wk = (const float*)d_in[2];
  const float* wv = (const float*)d_in[3];

  float* out  = (float*)d_out;
  float* ctx  = out;                                       // [4,2048,1024]
  float* attn = out + (size_t)NBATCH * S_LEN * D_DIM;      // [4,2048,2048]

  // workspace (shorts), ~94 MiB; pb aliases nh/nl (dead after scores GEMM)
  short* ws  = (short*)d_ws;
  short* xh  = ws;                                  // 8M
  short* xl  = xh + (size_t)8 * MEG;                // 8M
  short* wqh = xl + (size_t)8 * MEG;                // 1M Wq hi (original layout)
  short* wql = wqh + (size_t)1 * MEG;               // 1M Wq lo
  short* wkh = wql + (size_t)1 * MEG;               // 1M Wk hi
  short* wkl = wkh + (size_t)1 * MEG;               // 1M Wk lo
  short* wvt = wkl + (size_t)1 * MEG;               // 1M Wv^T hi
  short* mth = wvt + (size_t)1 * MEG;               // 1M M^T hi
  short* mtl = mth + (size_t)1 * MEG;               // 1M M^T lo
  short* nh  = mtl + (size_t)1 * MEG;               // 8M N~ hi
  short* nl  = nh + (size_t)8 * MEG;                // 8M N~ lo
  short* vt  = nl + (size_t)8 * MEG;                // 8M V^T [b,d,s]
  short* pb  = nh;                                  // 16M alias (nh+nl)
  float* fb  = (float*)(vt + (size_t)8 * MEG);
  float* mu  = fb;                                  // 1024
  float* sq  = fb + 1024;                           // 8192
  float* u   = sq + 8192;                           // 8192
  int*   ctr = (int*)(u + 8192);                    // sv work counter

  k_cvt<<<6144, 256, 0, stream>>>((const float4*)x, wq, wk, wv,
                                  xh, xl, wqh, wql, wkh, wkl, wvt);
  k_gemm_m<<<dim3(8, 8), 256, 0, stream>>>(wqh, wql, wkh, wkl, mth, mtl);
  k_mu<<<1024, 256, 0, stream>>>(mth, mtl, mu);
  k_rowstats<<<8192, 256, 0, stream>>>(xh, xl, mu, sq, u, ctr);
  k_gemm_n<<<dim3(8, 64), 256, 0, stream>>>(xh, xl, mth, mtl, sq, mu, nh, nl);
  k_gemm_sv512<<<512, 512, 0, stream>>>(nh, nl, xh, xl, sq, u, wvt, attn, vt, ctr);
  k_softmax<<<NBATCH * S_LEN, 256, 0, stream>>>(attn, pb);
  k_gemm_ctx<<<dim3(8, 16, 4), 256, 0, stream>>>(pb, vt, ctx);
}